// Round 2
// baseline (1580.003 us; speedup 1.0000x reference)
//
#include <hip/hip_runtime.h>
#include <hip/hip_bf16.h>

// ---------------------------------------------------------------------------
// VQ-VAE forward, all-f32 correctness-first baseline (round 2: ws footprint
// reduced to ~118 MB by aliasing S into h1's dead range).
// Stages: encoder GEMMs (relu x3, linear), S = Zenc @ E^T, row/col argmins
// with gathers, decoder GEMMs (leaky x3, tanh).
// ---------------------------------------------------------------------------

// activation: 0 none, 1 relu, 2 leaky(0.1), 3 tanh
template<int ACT, bool TRANSB>
__global__ __launch_bounds__(256)
void gemm_f32(const float* __restrict__ A, const float* __restrict__ W,
              const float* __restrict__ bias, float* __restrict__ C,
              int M, int K, int N)
{
    // BM=64, BN=64, BK=16; 256 threads, 4x4 micro-tile each.
    __shared__ float As[16][68];   // [kk][row], pad 68 keeps float4 alignment
    __shared__ float Ws[16][68];   // [kk][col]

    const int tid = threadIdx.x;
    const int tx  = tid & 15;
    const int ty  = tid >> 4;
    const int row0 = blockIdx.y * 64;
    const int col0 = blockIdx.x * 64;

    float acc[4][4];
#pragma unroll
    for (int i = 0; i < 4; ++i)
#pragma unroll
        for (int j = 0; j < 4; ++j) acc[i][j] = 0.f;

    // A-tile load mapping: thread -> (row 0..63, k-quad 0..3)
    const int a_row = tid >> 2;
    const int a_k4  = (tid & 3) << 2;
    // W-tile (no trans): thread -> (kk 0..15, col-quad 0..15)
    const int w_kk = tid >> 4;
    const int w_c4 = (tid & 15) << 2;
    // W-tile (trans, W is [N][K] row-major): thread -> (col 0..63, k-quad 0..3)
    const int t_col = tid >> 2;
    const int t_k4  = (tid & 3) << 2;

    for (int k0 = 0; k0 < K; k0 += 16) {
        // ---- stage A tile ----
        {
            const int gr = row0 + a_row;   // M is always a multiple of 64 here
            const int gk = k0 + a_k4;
            float4 av;
            if (gk + 3 < K) {
                av = *reinterpret_cast<const float4*>(A + (size_t)gr * K + gk);
            } else {
                float t0 = (gk + 0 < K) ? A[(size_t)gr * K + gk + 0] : 0.f;
                float t1 = (gk + 1 < K) ? A[(size_t)gr * K + gk + 1] : 0.f;
                float t2 = (gk + 2 < K) ? A[(size_t)gr * K + gk + 2] : 0.f;
                float t3 = (gk + 3 < K) ? A[(size_t)gr * K + gk + 3] : 0.f;
                av = make_float4(t0, t1, t2, t3);
            }
            As[a_k4 + 0][a_row] = av.x;
            As[a_k4 + 1][a_row] = av.y;
            As[a_k4 + 2][a_row] = av.z;
            As[a_k4 + 3][a_row] = av.w;
        }
        // ---- stage W tile ----
        if (!TRANSB) {
            const int gk = k0 + w_kk;
            const int gc = col0 + w_c4;
            float4 wv = make_float4(0.f, 0.f, 0.f, 0.f);
            if (gk < K) {
                if (gc + 3 < N) {
                    wv = *reinterpret_cast<const float4*>(W + (size_t)gk * N + gc);
                } else {
                    wv.x = (gc + 0 < N) ? W[(size_t)gk * N + gc + 0] : 0.f;
                    wv.y = (gc + 1 < N) ? W[(size_t)gk * N + gc + 1] : 0.f;
                    wv.z = (gc + 2 < N) ? W[(size_t)gk * N + gc + 2] : 0.f;
                    wv.w = (gc + 3 < N) ? W[(size_t)gk * N + gc + 3] : 0.f;
                }
            }
            *reinterpret_cast<float4*>(&Ws[w_kk][w_c4]) = wv;
        } else {
            const int gc = col0 + t_col;
            const int gk = k0 + t_k4;
            float4 wv = make_float4(0.f, 0.f, 0.f, 0.f);
            if (gc < N) {
                if (gk + 3 < K) {
                    wv = *reinterpret_cast<const float4*>(W + (size_t)gc * K + gk);
                } else {
                    wv.x = (gk + 0 < K) ? W[(size_t)gc * K + gk + 0] : 0.f;
                    wv.y = (gk + 1 < K) ? W[(size_t)gc * K + gk + 1] : 0.f;
                    wv.z = (gk + 2 < K) ? W[(size_t)gc * K + gk + 2] : 0.f;
                    wv.w = (gk + 3 < K) ? W[(size_t)gc * K + gk + 3] : 0.f;
                }
            }
            Ws[t_k4 + 0][t_col] = wv.x;
            Ws[t_k4 + 1][t_col] = wv.y;
            Ws[t_k4 + 2][t_col] = wv.z;
            Ws[t_k4 + 3][t_col] = wv.w;
        }
        __syncthreads();

#pragma unroll
        for (int kk = 0; kk < 16; ++kk) {
            float4 a = *reinterpret_cast<const float4*>(&As[kk][ty << 2]);
            float4 w = *reinterpret_cast<const float4*>(&Ws[kk][tx << 2]);
            acc[0][0] += a.x * w.x; acc[0][1] += a.x * w.y; acc[0][2] += a.x * w.z; acc[0][3] += a.x * w.w;
            acc[1][0] += a.y * w.x; acc[1][1] += a.y * w.y; acc[1][2] += a.y * w.z; acc[1][3] += a.y * w.w;
            acc[2][0] += a.z * w.x; acc[2][1] += a.z * w.y; acc[2][2] += a.z * w.z; acc[2][3] += a.z * w.w;
            acc[3][0] += a.w * w.x; acc[3][1] += a.w * w.y; acc[3][2] += a.w * w.z; acc[3][3] += a.w * w.w;
        }
        __syncthreads();
    }

#pragma unroll
    for (int i = 0; i < 4; ++i) {
        const int r = row0 + (ty << 2) + i;
#pragma unroll
        for (int j = 0; j < 4; ++j) {
            const int c = col0 + (tx << 2) + j;
            if (c < N) {
                float v = acc[i][j];
                if (bias) v += bias[c];
                if (ACT == 1) v = fmaxf(v, 0.f);
                else if (ACT == 2) v = (v > 0.f) ? v : 0.1f * v;
                else if (ACT == 3) v = tanhf(v);
                C[(size_t)r * N + c] = v;
            }
        }
    }
}

// sum of squares per row, rows of 64 floats
__global__ void row_norms64(const float* __restrict__ X, float* __restrict__ out, int rows)
{
    int r = blockIdx.x * blockDim.x + threadIdx.x;
    if (r >= rows) return;
    const float* p = X + (size_t)r * 64;
    float s = 0.f;
#pragma unroll
    for (int i = 0; i < 16; ++i) {
        float4 v = *reinterpret_cast<const float4*>(p + i * 4);
        s += v.x * v.x + v.y * v.y + v.z * v.z + v.w * v.w;
    }
    out[r] = s;
}

// For each of B rows of S [B,512]: argmin_k (En2[k] - 2 S[b][k]); gather E row.
__global__ __launch_bounds__(256)
void argmin_rows(const float* __restrict__ S, const float* __restrict__ En2,
                 const float* __restrict__ E, float* __restrict__ Zdec)
{
    const int wave = (blockIdx.x * blockDim.x + threadIdx.x) >> 6;  // 4 waves/block
    const int lane = threadIdx.x & 63;
    if (wave >= 16384) return;
    const float* Srow = S + (size_t)wave * 512;
    float best = INFINITY;
    int bidx = 0x7fffffff;
    for (int k = lane; k < 512; k += 64) {
        float v = En2[k] - 2.0f * Srow[k];
        if (v < best) { best = v; bidx = k; }   // ascending scan: first-min kept
    }
#pragma unroll
    for (int off = 32; off > 0; off >>= 1) {
        float ov = __shfl_down(best, off);
        int   oi = __shfl_down(bidx, off);
        if (ov < best || (ov == best && oi < bidx)) { best = ov; bidx = oi; }
    }
    bidx = __shfl(bidx, 0);
    Zdec[(size_t)wave * 64 + lane] = E[(size_t)bidx * 64 + lane];
}

// For each of 512 columns k of S: argmin_b (Zn2[b] - 2 S[b][k]); gather Zenc row.
__global__ __launch_bounds__(256)
void argmin_cols(const float* __restrict__ S, const float* __restrict__ Zn2,
                 const float* __restrict__ Zenc, float* __restrict__ Zemb)
{
    const int k = blockIdx.x;
    const int tid = threadIdx.x;
    float best = INFINITY;
    int bidx = 0x7fffffff;
    for (int b = tid; b < 16384; b += 256) {
        float v = Zn2[b] - 2.0f * S[(size_t)b * 512 + k];
        if (v < best) { best = v; bidx = b; }   // ascending scan: first-min kept
    }
    __shared__ float vs[256];
    __shared__ int   is[256];
    vs[tid] = best; is[tid] = bidx;
    __syncthreads();
    for (int s = 128; s > 0; s >>= 1) {
        if (tid < s) {
            if (vs[tid + s] < vs[tid] ||
                (vs[tid + s] == vs[tid] && is[tid + s] < is[tid])) {
                vs[tid] = vs[tid + s]; is[tid] = is[tid + s];
            }
        }
        __syncthreads();
    }
    const int idx = is[0];
    if (tid < 64) Zemb[(size_t)k * 64 + tid] = Zenc[(size_t)idx * 64 + tid];
}

extern "C" void kernel_launch(void* const* d_in, const int* in_sizes, int n_in,
                              void* d_out, int out_size, void* d_ws, size_t ws_size,
                              hipStream_t stream)
{
    const float* X  = (const float*)d_in[0];
    const float* W1 = (const float*)d_in[1];
    const float* b1 = (const float*)d_in[2];
    const float* W2 = (const float*)d_in[3];
    const float* b2 = (const float*)d_in[4];
    const float* W3 = (const float*)d_in[5];
    const float* b3 = (const float*)d_in[6];
    const float* W4 = (const float*)d_in[7];
    const float* b4 = (const float*)d_in[8];
    const float* E  = (const float*)d_in[9];
    const float* V1 = (const float*)d_in[10];
    const float* c1 = (const float*)d_in[11];
    const float* V2 = (const float*)d_in[12];
    const float* c2 = (const float*)d_in[13];
    const float* V3 = (const float*)d_in[14];
    const float* c3 = (const float*)d_in[15];
    const float* V4 = (const float*)d_in[16];
    const float* c4 = (const float*)d_in[17];

    float* out  = (float*)d_out;
    float* Xrec = out;                  // 16384*784
    float* Zenc = out + 12845056;       // 16384*64
    float* Zdec = out + 13893632;       // 16384*64
    float* Zemb = out + 14942208;       // 512*64

    // Workspace layout (bytes), peak ~118 MB.
    // Liveness: h1 last read -> h2 GEMM; S (aliases h1) written after that,
    // last read by argmins; g3 (= h1 region) first written after argmins.
    char* ws = (char*)d_ws;
    float* h1  = (float*)(ws + 0);          // 16384x1000 (65,536,000 B)  -> also S, g3
    float* h2  = (float*)(ws + 65536000);   // 16384x500  (32,768,000 B)  -> also g2
    float* h3  = (float*)(ws + 98304000);   // 16384x300  (19,660,800 B)  -> also g1
    float* Zn2 = (float*)(ws + 117964800);  // 16384      (65,536 B)
    float* En2 = (float*)(ws + 118030336);  // 512        (2,048 B)
    float* S   = h1;                        // 16384x512  (33,554,432 B) aliases h1
    float* g1 = h3;
    float* g2 = h2;
    float* g3 = h1;

    const dim3 blk(256);

    // ---- encoder (f32: argmin fidelity requires it) ----
    gemm_f32<1, false><<<dim3(16, 256), blk, 0, stream>>>(X,  W1, b1, h1, 16384, 784,  1000);
    gemm_f32<1, false><<<dim3(8,  256), blk, 0, stream>>>(h1, W2, b2, h2, 16384, 1000, 500);
    gemm_f32<1, false><<<dim3(5,  256), blk, 0, stream>>>(h2, W3, b3, h3, 16384, 500,  300);
    gemm_f32<0, false><<<dim3(1,  256), blk, 0, stream>>>(h3, W4, b4, Zenc, 16384, 300, 64);

    // ---- nearest-neighbor via one shared inner-product matrix ----
    row_norms64<<<dim3(8),  dim3(64), 0, stream>>>(E,    En2, 512);
    row_norms64<<<dim3(64), blk,      0, stream>>>(Zenc, Zn2, 16384);
    gemm_f32<0, true><<<dim3(8, 256), blk, 0, stream>>>(Zenc, E, nullptr, S, 16384, 64, 512);
    argmin_rows<<<dim3(4096), blk, 0, stream>>>(S, En2, E, Zdec);
    argmin_cols<<<dim3(512),  blk, 0, stream>>>(S, Zn2, Zenc, Zemb);

    // ---- decoder ----
    gemm_f32<2, false><<<dim3(5,  256), blk, 0, stream>>>(Zdec, V1, c1, g1, 16384, 64,   300);
    gemm_f32<2, false><<<dim3(8,  256), blk, 0, stream>>>(g1,   V2, c2, g2, 16384, 300,  500);
    gemm_f32<2, false><<<dim3(16, 256), blk, 0, stream>>>(g2,   V3, c3, g3, 16384, 500,  1000);
    gemm_f32<3, false><<<dim3(13, 256), blk, 0, stream>>>(g3,   V4, c4, Xrec, 16384, 1000, 784);
}

// Round 3
// 747.241 us; speedup vs baseline: 2.1144x; 2.1144x over previous
//
#include <hip/hip_runtime.h>
#include <hip/hip_bf16.h>

// ---------------------------------------------------------------------------
// VQ-VAE forward. Encoder: split-bf16 (hi+lo, 3-MFMA) GEMMs for f32-class
// accuracy (argmin fidelity). Decoder: plain bf16 MFMA. S-matrix/argmins f32.
// ---------------------------------------------------------------------------

typedef __attribute__((ext_vector_type(8))) short short8v;
typedef __attribute__((ext_vector_type(4))) float f32x4;

__device__ inline ushort f2bf(float v) {
    __hip_bfloat16 h = __float2bfloat16(v);
    return *reinterpret_cast<ushort*>(&h);
}
__device__ inline float bf2f(ushort s) {
    __hip_bfloat16 h;
    *reinterpret_cast<ushort*>(&h) = s;
    return __bfloat162float(h);
}

// ---------------------------------------------------------------------------
// MFMA GEMM: C[M,N] = act(A[M,K] @ W[K,N] + bias)
// A: bf16 (hi[,lo]) row-major with padded stride Kp.
// W: pre-tiled bf16 [kbg][N][8] (k = kbg*8 + j), zero-padded to ceil(K/32)*4 kbgs.
// OMODE: 0 = f32 out (ldc=N), 1 = bf16 out (ldc=Np), 2 = split bf16 hi/lo out.
// ACT: 0 none, 1 relu, 2 leaky(0.1), 3 tanh
// ---------------------------------------------------------------------------
template<int ACT, bool SPLIT, int OMODE>
__global__ __launch_bounds__(256)
void gemm_mfma(const ushort* __restrict__ Ahi, const ushort* __restrict__ Alo,
               const ushort* __restrict__ Bhi, const ushort* __restrict__ Blo,
               const float* __restrict__ bias,
               float* __restrict__ Cf, ushort* __restrict__ Chi, ushort* __restrict__ Clo,
               int M, int K, int N, int Kp, int Np)
{
    __shared__ short Ah[4][128][8];                 // [kb][row][j], k = k0 + kb*8 + j
    __shared__ short Bh[4][128][8];                 // [kb][col][j]
    __shared__ short Al[SPLIT ? 4 : 1][128][8];
    __shared__ short Bl[SPLIT ? 4 : 1][128][8];

    const int tid  = threadIdx.x;
    const int lane = tid & 63;
    const int wid  = tid >> 6;
    const int wr   = (wid >> 1) * 64;               // wave row origin in tile
    const int wc   = (wid & 1) * 64;                // wave col origin in tile
    const int row0 = blockIdx.y * 128;
    const int col0 = blockIdx.x * 128;

    f32x4 acc[4][4];
#pragma unroll
    for (int m = 0; m < 4; ++m)
#pragma unroll
        for (int n = 0; n < 4; ++n) acc[m][n] = (f32x4){0.f, 0.f, 0.f, 0.f};

    const int ar = tid >> 1;                        // A stage: row 0..127
    const int ak = (tid & 1) << 4;                  // k offset 0 or 16
    const ushort* pAh = Ahi + (size_t)(row0 + ar) * Kp;
    const ushort* pAl = SPLIT ? (Alo + (size_t)(row0 + ar) * Kp) : (const ushort*)nullptr;

    const int fr = lane & 15;                       // fragment row/col within 16
    const int kq = lane >> 4;                       // k-quad 0..3

    for (int k0 = 0; k0 < K; k0 += 32) {
        // ---- stage A (row ar, k kg..kg+15 -> kb blocks ak/8, ak/8+1) ----
        {
            const int kg = k0 + ak;
            const int kb = ak >> 3;                 // 0 or 2
            if (kg + 16 <= K) {
                *(short8v*)&Ah[kb][ar][0]     = *(const short8v*)(pAh + kg);
                *(short8v*)&Ah[kb + 1][ar][0] = *(const short8v*)(pAh + kg + 8);
                if (SPLIT) {
                    *(short8v*)&Al[kb][ar][0]     = *(const short8v*)(pAl + kg);
                    *(short8v*)&Al[kb + 1][ar][0] = *(const short8v*)(pAl + kg + 8);
                }
            } else {
                short t0[16];
#pragma unroll
                for (int j = 0; j < 16; ++j) t0[j] = (kg + j < K) ? (short)pAh[kg + j] : (short)0;
                *(short8v*)&Ah[kb][ar][0]     = *(short8v*)&t0[0];
                *(short8v*)&Ah[kb + 1][ar][0] = *(short8v*)&t0[8];
                if (SPLIT) {
#pragma unroll
                    for (int j = 0; j < 16; ++j) t0[j] = (kg + j < K) ? (short)pAl[kg + j] : (short)0;
                    *(short8v*)&Al[kb][ar][0]     = *(short8v*)&t0[0];
                    *(short8v*)&Al[kb + 1][ar][0] = *(short8v*)&t0[8];
                }
            }
        }
        // ---- stage B from pre-tiled Wt: 16B chunk per (kb,col) ----
        {
            const int kbase = k0 >> 3;
#pragma unroll
            for (int h = 0; h < 2; ++h) {
                const int id = tid + (h << 8);
                const int kb = id >> 7;
                const int c  = id & 127;
                const int gc = col0 + c;
                short8v v  = (short8v){0, 0, 0, 0, 0, 0, 0, 0};
                short8v vl = v;
                if (gc < N) {
                    v = *(const short8v*)(Bhi + ((size_t)(kbase + kb) * N + gc) * 8);
                    if (SPLIT) vl = *(const short8v*)(Blo + ((size_t)(kbase + kb) * N + gc) * 8);
                }
                *(short8v*)&Bh[kb][c][0] = v;
                if (SPLIT) *(short8v*)&Bl[kb][c][0] = vl;
            }
        }
        __syncthreads();

        short8v a_h[4], b_h[4], a_l[4], b_l[4];
#pragma unroll
        for (int m = 0; m < 4; ++m) {
            a_h[m] = *(const short8v*)&Ah[kq][wr + m * 16 + fr][0];
            if (SPLIT) a_l[m] = *(const short8v*)&Al[kq][wr + m * 16 + fr][0];
        }
#pragma unroll
        for (int n = 0; n < 4; ++n) {
            b_h[n] = *(const short8v*)&Bh[kq][wc + n * 16 + fr][0];
            if (SPLIT) b_l[n] = *(const short8v*)&Bl[kq][wc + n * 16 + fr][0];
        }
#pragma unroll
        for (int m = 0; m < 4; ++m)
#pragma unroll
            for (int n = 0; n < 4; ++n) {
                acc[m][n] = __builtin_amdgcn_mfma_f32_16x16x32_bf16(a_h[m], b_h[n], acc[m][n], 0, 0, 0);
                if (SPLIT) {
                    acc[m][n] = __builtin_amdgcn_mfma_f32_16x16x32_bf16(a_h[m], b_l[n], acc[m][n], 0, 0, 0);
                    acc[m][n] = __builtin_amdgcn_mfma_f32_16x16x32_bf16(a_l[m], b_h[n], acc[m][n], 0, 0, 0);
                }
            }
        __syncthreads();
    }

    // ---- epilogue: C/D layout col=lane&15, row=(lane>>4)*4+reg ----
#pragma unroll
    for (int n = 0; n < 4; ++n) {
        const int c = col0 + wc + n * 16 + fr;
        if (c >= N) continue;
        const float bv = bias ? bias[c] : 0.f;
#pragma unroll
        for (int m = 0; m < 4; ++m) {
#pragma unroll
            for (int i = 0; i < 4; ++i) {
                const int r = row0 + wr + m * 16 + kq * 4 + i;
                float v = acc[m][n][i] + bv;
                if (ACT == 1) v = fmaxf(v, 0.f);
                else if (ACT == 2) v = (v > 0.f) ? v : 0.1f * v;
                else if (ACT == 3) v = tanhf(v);
                if (OMODE == 0) {
                    Cf[(size_t)r * N + c] = v;
                } else {
                    const ushort h = f2bf(v);
                    Chi[(size_t)r * Np + c] = h;
                    if (OMODE == 2) Clo[(size_t)r * Np + c] = f2bf(v - bf2f(h));
                }
            }
        }
    }
}

// ---------------------------------------------------------------------------
// f32 VALU GEMM kept for S = Zenc @ E^T (argmin needs f32 fidelity; 1 GF only)
// ---------------------------------------------------------------------------
__global__ __launch_bounds__(256)
void gemm_f32_bt(const float* __restrict__ A, const float* __restrict__ W,
                 float* __restrict__ C, int M, int K, int N)
{
    __shared__ float As[16][68];
    __shared__ float Ws[16][68];

    const int tid = threadIdx.x;
    const int tx = tid & 15, ty = tid >> 4;
    const int row0 = blockIdx.y * 64, col0 = blockIdx.x * 64;

    float acc[4][4];
#pragma unroll
    for (int i = 0; i < 4; ++i)
#pragma unroll
        for (int j = 0; j < 4; ++j) acc[i][j] = 0.f;

    const int a_row = tid >> 2, a_k4 = (tid & 3) << 2;
    const int t_col = tid >> 2, t_k4 = (tid & 3) << 2;

    for (int k0 = 0; k0 < K; k0 += 16) {
        {
            const int gr = row0 + a_row, gk = k0 + a_k4;
            float4 av = *reinterpret_cast<const float4*>(A + (size_t)gr * K + gk); // K=64 mult of 16
            As[a_k4 + 0][a_row] = av.x; As[a_k4 + 1][a_row] = av.y;
            As[a_k4 + 2][a_row] = av.z; As[a_k4 + 3][a_row] = av.w;
        }
        {
            const int gc = col0 + t_col, gk = k0 + t_k4;
            float4 wv = *reinterpret_cast<const float4*>(W + (size_t)gc * K + gk);
            Ws[t_k4 + 0][t_col] = wv.x; Ws[t_k4 + 1][t_col] = wv.y;
            Ws[t_k4 + 2][t_col] = wv.z; Ws[t_k4 + 3][t_col] = wv.w;
        }
        __syncthreads();
#pragma unroll
        for (int kk = 0; kk < 16; ++kk) {
            float4 a = *reinterpret_cast<const float4*>(&As[kk][ty << 2]);
            float4 w = *reinterpret_cast<const float4*>(&Ws[kk][tx << 2]);
            acc[0][0] += a.x * w.x; acc[0][1] += a.x * w.y; acc[0][2] += a.x * w.z; acc[0][3] += a.x * w.w;
            acc[1][0] += a.y * w.x; acc[1][1] += a.y * w.y; acc[1][2] += a.y * w.z; acc[1][3] += a.y * w.w;
            acc[2][0] += a.z * w.x; acc[2][1] += a.z * w.y; acc[2][2] += a.z * w.z; acc[2][3] += a.z * w.w;
            acc[3][0] += a.w * w.x; acc[3][1] += a.w * w.y; acc[3][2] += a.w * w.z; acc[3][3] += a.w * w.w;
        }
        __syncthreads();
    }
#pragma unroll
    for (int i = 0; i < 4; ++i) {
        const int r = row0 + (ty << 2) + i;
#pragma unroll
        for (int j = 0; j < 4; ++j) {
            const int c = col0 + (tx << 2) + j;
            C[(size_t)r * N + c] = acc[i][j];
        }
    }
}

// sum of squares per row, rows of 64 floats
__global__ void row_norms64(const float* __restrict__ X, float* __restrict__ out, int rows)
{
    int r = blockIdx.x * blockDim.x + threadIdx.x;
    if (r >= rows) return;
    const float* p = X + (size_t)r * 64;
    float s = 0.f;
#pragma unroll
    for (int i = 0; i < 16; ++i) {
        float4 v = *reinterpret_cast<const float4*>(p + i * 4);
        s += v.x * v.x + v.y * v.y + v.z * v.z + v.w * v.w;
    }
    out[r] = s;
}

// row argmin over 512 codebook entries; gather E row (f32 + bf16 copies).
__global__ __launch_bounds__(256)
void argmin_rows(const float* __restrict__ S, const float* __restrict__ En2,
                 const float* __restrict__ E, float* __restrict__ Zdec,
                 ushort* __restrict__ Zdec_bf)
{
    const int wave = (blockIdx.x * blockDim.x + threadIdx.x) >> 6;
    const int lane = threadIdx.x & 63;
    if (wave >= 16384) return;
    const float* Srow = S + (size_t)wave * 512;
    float best = INFINITY;
    int bidx = 0x7fffffff;
    for (int k = lane; k < 512; k += 64) {
        float v = En2[k] - 2.0f * Srow[k];
        if (v < best) { best = v; bidx = k; }
    }
#pragma unroll
    for (int off = 32; off > 0; off >>= 1) {
        float ov = __shfl_down(best, off);
        int   oi = __shfl_down(bidx, off);
        if (ov < best || (ov == best && oi < bidx)) { best = ov; bidx = oi; }
    }
    bidx = __shfl(bidx, 0);
    const float val = E[(size_t)bidx * 64 + lane];
    Zdec[(size_t)wave * 64 + lane] = val;
    Zdec_bf[(size_t)wave * 64 + lane] = f2bf(val);
}

// column argmin over 16384 rows; gather Zenc row.
__global__ __launch_bounds__(256)
void argmin_cols(const float* __restrict__ S, const float* __restrict__ Zn2,
                 const float* __restrict__ Zenc, float* __restrict__ Zemb)
{
    const int k = blockIdx.x;
    const int tid = threadIdx.x;
    float best = INFINITY;
    int bidx = 0x7fffffff;
    for (int b = tid; b < 16384; b += 256) {
        float v = Zn2[b] - 2.0f * S[(size_t)b * 512 + k];
        if (v < best) { best = v; bidx = b; }
    }
    __shared__ float vs[256];
    __shared__ int   is[256];
    vs[tid] = best; is[tid] = bidx;
    __syncthreads();
    for (int s = 128; s > 0; s >>= 1) {
        if (tid < s) {
            if (vs[tid + s] < vs[tid] ||
                (vs[tid + s] == vs[tid] && is[tid + s] < is[tid])) {
                vs[tid] = vs[tid + s]; is[tid] = is[tid + s];
            }
        }
        __syncthreads();
    }
    const int idx = is[0];
    if (tid < 64) Zemb[(size_t)k * 64 + tid] = Zenc[(size_t)idx * 64 + tid];
}

// elementwise f32 -> split bf16 (hi, lo)
__global__ void conv_split(const float* __restrict__ in, ushort* __restrict__ hi,
                           ushort* __restrict__ lo, long n)
{
    for (long i = blockIdx.x * 256L + threadIdx.x; i < n; i += (long)gridDim.x * 256L) {
        const float v = in[i];
        const ushort h = f2bf(v);
        hi[i] = h;
        lo[i] = f2bf(v - bf2f(h));
    }
}

// tile weights [K][N] -> [kbgTot][N][8] bf16 (k = kb*8+j), zero-pad k >= K
template<bool SPLIT>
__global__ void prep_w(const float* __restrict__ W, ushort* __restrict__ hi,
                       ushort* __restrict__ lo, int K, int N, int kbgTot)
{
    const long total = (long)kbgTot * N * 8;
    for (long i = blockIdx.x * 256L + threadIdx.x; i < total; i += (long)gridDim.x * 256L) {
        const int j = (int)(i & 7);
        const long t = i >> 3;
        const int n  = (int)(t % N);
        const int kb = (int)(t / N);
        const int k  = kb * 8 + j;
        const float v = (k < K) ? W[(size_t)k * N + n] : 0.f;
        const ushort h = f2bf(v);
        hi[i] = h;
        if (SPLIT) lo[i] = f2bf(v - bf2f(h));
    }
}

extern "C" void kernel_launch(void* const* d_in, const int* in_sizes, int n_in,
                              void* d_out, int out_size, void* d_ws, size_t ws_size,
                              hipStream_t stream)
{
    const float* X  = (const float*)d_in[0];
    const float* W1 = (const float*)d_in[1];
    const float* b1 = (const float*)d_in[2];
    const float* W2 = (const float*)d_in[3];
    const float* b2 = (const float*)d_in[4];
    const float* W3 = (const float*)d_in[5];
    const float* b3 = (const float*)d_in[6];
    const float* W4 = (const float*)d_in[7];
    const float* b4 = (const float*)d_in[8];
    const float* E  = (const float*)d_in[9];
    const float* V1 = (const float*)d_in[10];
    const float* c1 = (const float*)d_in[11];
    const float* V2 = (const float*)d_in[12];
    const float* c2 = (const float*)d_in[13];
    const float* V3 = (const float*)d_in[14];
    const float* c3 = (const float*)d_in[15];
    const float* V4 = (const float*)d_in[16];
    const float* c4 = (const float*)d_in[17];

    float* out  = (float*)d_out;
    float* Xrec = out;                  // 16384*784
    float* Zenc = out + 12845056;       // 16384*64
    float* Zdec = out + 13893632;
    float* Zemb = out + 14942208;

    char* ws = (char*)d_ws;
    // Slab A [0, 51.38M): Xhi/Xlo -> h2hi/lo -> S -> g3
    ushort* Xhi  = (ushort*)(ws + 0);
    ushort* Xlo  = (ushort*)(ws + 25690112);
    ushort* h2h  = (ushort*)(ws + 0);          // 16384x504
    ushort* h2l  = (ushort*)(ws + 16515072);
    float*  S    = (float*)(ws + 0);           // 16384x512
    ushort* g3   = (ushort*)(ws + 0);          // 16384x1000
    // Slab B [51.38M, 84.15M): h1lo -> h3hi/lo -> g1,g2
    ushort* h1l  = (ushort*)(ws + 51380224);   // 16384x1000
    ushort* h3h  = (ushort*)(ws + 51380224);   // 16384x304
    ushort* h3l  = (ushort*)(ws + 61341696);
    ushort* g1   = (ushort*)(ws + 51380224);   // 16384x304
    ushort* g2   = (ushort*)(ws + 61341696);   // 16384x504
    // h1hi parks in d_out's Xrec slab (dead before dec4 writes Xrec)
    ushort* h1h  = (ushort*)d_out;             // 16384x1000 bf16 = 32.77MB < 51.38MB
    // Tail [84.15M, 95.25M): persistent small buffers
    float*  Zn2  = (float*)(ws + 84148224);
    float*  En2  = (float*)(ws + 84213760);
    ushort* Zdcb = (ushort*)(ws + 84215808);   // 16384x64 bf16
    ushort* Wt1h = (ushort*)(ws + 86312960);   // 100 kbg x 1000 x 8
    ushort* Wt1l = (ushort*)(ws + 87912960);
    ushort* Wt2h = (ushort*)(ws + 89512960);   // 128 x 500 x 8
    ushort* Wt2l = (ushort*)(ws + 90536960);
    ushort* Wt3h = (ushort*)(ws + 91560960);   // 64 x 300 x 8
    ushort* Wt3l = (ushort*)(ws + 91868160);
    ushort* Wt4h = (ushort*)(ws + 92175360);   // 40 x 64 x 8
    ushort* Wt4l = (ushort*)(ws + 92216320);
    ushort* Vt1  = (ushort*)(ws + 92257280);   // 8 x 300 x 8
    ushort* Vt2  = (ushort*)(ws + 92295680);   // 40 x 500 x 8
    ushort* Vt3  = (ushort*)(ws + 92615680);   // 64 x 1000 x 8
    ushort* Vt4  = (ushort*)(ws + 93639680);   // 128 x 784 x 8

    const dim3 blk(256);

    // ---- input/weight conversion & tiling ----
    conv_split<<<dim3(2048), blk, 0, stream>>>(X, Xhi, Xlo, 16384L * 784);
    prep_w<true ><<<dim3(512), blk, 0, stream>>>(W1, Wt1h, Wt1l, 784, 1000, 100);
    prep_w<true ><<<dim3(512), blk, 0, stream>>>(W2, Wt2h, Wt2l, 1000, 500, 128);
    prep_w<true ><<<dim3(256), blk, 0, stream>>>(W3, Wt3h, Wt3l, 500, 300, 64);
    prep_w<true ><<<dim3(64),  blk, 0, stream>>>(W4, Wt4h, Wt4l, 300, 64, 40);
    prep_w<false><<<dim3(64),  blk, 0, stream>>>(V1, Vt1, nullptr, 64, 300, 8);
    prep_w<false><<<dim3(256), blk, 0, stream>>>(V2, Vt2, nullptr, 300, 500, 40);
    prep_w<false><<<dim3(512), blk, 0, stream>>>(V3, Vt3, nullptr, 500, 1000, 64);
    prep_w<false><<<dim3(512), blk, 0, stream>>>(V4, Vt4, nullptr, 1000, 784, 128);

    // ---- encoder: split-bf16 (3-MFMA), f32-class accuracy ----
    gemm_mfma<1, true, 2><<<dim3(8, 128), blk, 0, stream>>>(Xhi, Xlo, Wt1h, Wt1l, b1, nullptr, h1h, h1l, 16384, 784, 1000, 784, 1000);
    gemm_mfma<1, true, 2><<<dim3(4, 128), blk, 0, stream>>>(h1h, h1l, Wt2h, Wt2l, b2, nullptr, h2h, h2l, 16384, 1000, 500, 1000, 504);
    gemm_mfma<1, true, 2><<<dim3(3, 128), blk, 0, stream>>>(h2h, h2l, Wt3h, Wt3l, b3, nullptr, h3h, h3l, 16384, 500, 300, 504, 304);
    gemm_mfma<0, true, 0><<<dim3(1, 128), blk, 0, stream>>>(h3h, h3l, Wt4h, Wt4l, b4, Zenc, nullptr, nullptr, 16384, 300, 64, 304, 64);

    // ---- nearest-neighbor (f32) ----
    row_norms64<<<dim3(8),  dim3(64), 0, stream>>>(E,    En2, 512);
    row_norms64<<<dim3(64), blk,      0, stream>>>(Zenc, Zn2, 16384);
    gemm_f32_bt<<<dim3(8, 256), blk, 0, stream>>>(Zenc, E, S, 16384, 64, 512);
    argmin_rows<<<dim3(4096), blk, 0, stream>>>(S, En2, E, Zdec, Zdcb);
    argmin_cols<<<dim3(512),  blk, 0, stream>>>(S, Zn2, Zenc, Zemb);

    // ---- decoder: plain bf16 MFMA ----
    gemm_mfma<2, false, 1><<<dim3(3, 128), blk, 0, stream>>>(Zdcb, nullptr, Vt1, nullptr, c1, nullptr, g1, nullptr, 16384, 64, 300, 64, 304);
    gemm_mfma<2, false, 1><<<dim3(4, 128), blk, 0, stream>>>(g1, nullptr, Vt2, nullptr, c2, nullptr, g2, nullptr, 16384, 300, 500, 304, 504);
    gemm_mfma<2, false, 1><<<dim3(8, 128), blk, 0, stream>>>(g2, nullptr, Vt3, nullptr, c3, nullptr, g3, nullptr, 16384, 500, 1000, 504, 1000);
    gemm_mfma<3, false, 0><<<dim3(7, 128), blk, 0, stream>>>(g3, nullptr, Vt4, nullptr, c4, Xrec, nullptr, nullptr, 16384, 1000, 784, 1000, 784);
}